// Round 10
// baseline (1568.211 us; speedup 1.0000x reference)
//
#include <hip/hip_runtime.h>
#include <math.h>

typedef float f32x2 __attribute__((ext_vector_type(2)));

#define NPTS 32768          // b*h*w*d = 1*32*32*32
#define NE   2048
#define ED   16
#define WAVES 16
#define CHUNK (NE / WAVES)   // 128
#define HALFC (CHUNK / 2)    // 64

// exp2-domain temperature constants (exp(x*T) == exp2(x*T*log2e))
#define KT2 20.60992915555662f          // (1/0.07) * log2(e)
#define KE2 144.26950408889634f         // 100 * log2(e)
#define LN2 0.69314718055994531f

// output layout (floats, concatenated in return order)
#define OFF_SOFT 0
#define OFF_LOSS 524288
#define OFF_HARD 524289
#define OFF_IDX  1048577

// workspace layout (floats)
#define WS_EMB  0        // 2048*16 normalized embedding
#define WS_PSUM 32768    // 2048 column sums of ent-probs
#define WS_SSUM 34816    // 1 scalar

__device__ __forceinline__ float fexp2(float x) {
#if __has_builtin(__builtin_amdgcn_exp2f)
    return __builtin_amdgcn_exp2f(x);   // v_exp_f32
#else
    float r; asm("v_exp_f32 %0, %1" : "=v"(r) : "v"(x)); return r;
#endif
}

// dot over 16 channels (codeword as 4x float4); f32x2 accumulator partition
// identical to R8's dot16 (a.x: c0,c4,c8,c12; a.y: c1,c5,...; b: c2,c3,...;
// final (a.x+a.y)+(b.x+b.y)) -> logits bit-identical, argmax unchanged.
__device__ __forceinline__ float dot16q(const f32x2 zn2[8], const float4 e[4]) {
    f32x2 a = zn2[0] * f32x2{e[0].x, e[0].y};
    f32x2 b = zn2[1] * f32x2{e[0].z, e[0].w};
    a = __builtin_elementwise_fma(zn2[2], f32x2{e[1].x, e[1].y}, a);
    b = __builtin_elementwise_fma(zn2[3], f32x2{e[1].z, e[1].w}, b);
    a = __builtin_elementwise_fma(zn2[4], f32x2{e[2].x, e[2].y}, a);
    b = __builtin_elementwise_fma(zn2[5], f32x2{e[2].z, e[2].w}, b);
    a = __builtin_elementwise_fma(zn2[6], f32x2{e[3].x, e[3].y}, a);
    b = __builtin_elementwise_fma(zn2[7], f32x2{e[3].z, e[3].w}, b);
    return (a.x + a.y) + (b.x + b.y);
}

__global__ __launch_bounds__(256) void vq_prep(const float* __restrict__ emb,
                                               float* __restrict__ ws) {
    int t = blockIdx.x * 256 + threadIdx.x;
    if (t < NE) {
        float v[ED]; float s = 0.f;
        #pragma unroll
        for (int c = 0; c < ED; ++c) { v[c] = emb[t * ED + c]; s += v[c] * v[c]; }
        float inv = 1.0f / fmaxf(sqrtf(s), 1e-12f);
        #pragma unroll
        for (int c = 0; c < ED; ++c) ws[WS_EMB + t * ED + c] = v[c] * inv;
        ws[WS_PSUM + t] = 0.f;
    }
    if (t == 0) ws[WS_SSUM] = 0.f;
}

__global__ __launch_bounds__(1024, 4) void vq_main(const float* __restrict__ z,
                                                   const float* __restrict__ embN,
                                                   float* __restrict__ psum,
                                                   float* __restrict__ ssum,
                                                   float* __restrict__ out) {
    const int lane = threadIdx.x & 63;
    const int w    = threadIdx.x >> 6;      // VGPR-typed: keeps E4 loads in VMEM
    const int n    = blockIdx.x * 64 + lane;

    __shared__ float sm [WAVES][64];
    __shared__ float ss1[WAVES][64];
    __shared__ int   sam[WAVES][64];
    __shared__ float sst[WAVES][64];
    __shared__ float sr [WAVES][64];
    __shared__ float svec[WAVES / 2][64][ED + 1];   // +1 pad: conflict-free

    // ---- load z row (channel-strided) and l2-normalize (bit-identical to r8)
    float zn[ED]; float s = 0.f;
    #pragma unroll
    for (int c = 0; c < ED; ++c) { float v = z[c * NPTS + n]; zn[c] = v; s += v * v; }
    float rinv = 1.0f / fmaxf(sqrtf(s), 1e-12f);
    f32x2 zn2[8];
    #pragma unroll
    for (int q = 0; q < 8; ++q) zn2[q] = f32x2{zn[2 * q] * rinv, zn[2 * q + 1] * rinv};

    const int kbase = w * CHUNK;
    const float4* __restrict__ E4 = (const float4*)embN;  // 4 float4 per codeword

    #define RELOAD(EB, KK)                                               \
        {  _Pragma("unroll")                                             \
           for (int q = 0; q < 4; ++q) EB[q] = E4[(size_t)(KK) * 4 + q]; }

    // ---- pass 1: dual-chain branchless online max/argmax/S1,
    //      VMEM broadcast loads, 2-deep prefetch ring per chain
    float m0 = -2.f, m1 = -2.f, s10 = 0.f, s11 = 0.f;   // cosines in [-1,1]
    int am0 = kbase, am1 = kbase + HALFC;
    {
        float4 A0[4], A1[4], B0[4], B1[4];
        RELOAD(A0, kbase);
        RELOAD(B0, kbase + HALFC);
        RELOAD(A1, kbase + 1);
        RELOAD(B1, kbase + HALFC + 1);
        #define P1STEP(EB, KK, MM, SS, AA)                               \
            {  float l  = dot16q(zn2, EB);                               \
               float e0 = fexp2(-fabsf(l - MM) * KE2);                   \
               bool  g  = l > MM;                                        \
               AA = g ? (KK) : AA;                                       \
               MM = fmaxf(MM, l);                                        \
               SS = g ? fmaf(SS, e0, 1.0f) : (SS + e0); }
        for (int i = 0; i < HALFC; i += 2) {
            // tail reloads run <=2 codewords past the chunk (w=15: into the
            // psum region of ws) -- mapped memory, values never consumed.
            P1STEP(A0, kbase + i, m0, s10, am0);
            RELOAD(A0, kbase + i + 2);
            P1STEP(B0, kbase + HALFC + i, m1, s11, am1);
            RELOAD(B0, kbase + HALFC + i + 2);
            P1STEP(A1, kbase + i + 1, m0, s10, am0);
            RELOAD(A1, kbase + i + 3);
            P1STEP(B1, kbase + HALFC + i + 1, m1, s11, am1);
            RELOAD(B1, kbase + HALFC + i + 3);
        }
        #undef P1STEP
    }
    {   // merge chains; chain0 owns lower k, so strict > keeps first max
        float em = fexp2(-fabsf(m1 - m0) * KE2);
        bool  g  = m1 > m0;
        sam[w][lane] = g ? am1 : am0;
        sm [w][lane] = fmaxf(m0, m1);
        ss1[w][lane] = g ? fmaf(s10, em, s11) : fmaf(s11, em, s10);
    }
    __syncthreads();

    // ---- flash-combine the 16 wave-chunks (every thread, own row)
    float M = sm[0][lane]; int AM = sam[0][lane];
    #pragma unroll
    for (int j = 1; j < WAVES; ++j) {
        float mj = sm[j][lane];
        if (mj > M) { M = mj; AM = sam[j][lane]; }    // ascending k: > keeps first
    }
    float S1t = 0.f;
    #pragma unroll
    for (int j = 0; j < WAVES; ++j)
        S1t += ss1[j][lane] * fexp2((sm[j][lane] - M) * KE2);
    float invS1 = 1.0f / S1t;

    // ---- pass 2: z_q_soft partials, tau-sum, entropy dot, avg_probs columns;
    //      4-deep VMEM prefetch ring (C0..C3), unrolled x4 (static indices)
    f32x2 vec2[8];
    #pragma unroll
    for (int q = 0; q < 8; ++q) vec2[q] = f32x2{0.f, 0.f};
    float St = 0.f, r = 0.f;
    {
        float4 C0[4], C1[4], C2[4], C3[4];
        RELOAD(C0, kbase);
        RELOAD(C1, kbase + 1);
        RELOAD(C2, kbase + 2);
        RELOAD(C3, kbase + 3);
        #define P2STEP(EB, POUT)                                         \
            {  float l  = dot16q(zn2, EB);                               \
               float aa = l - M;                                         \
               float aK = aa * KE2;                                      \
               float rt = fexp2(aa * KT2);                               \
               St += rt;                                                 \
               float p  = fexp2(aK) * invS1;                             \
               r = fmaf(p, aK, r);                                       \
               f32x2 rt2 = {rt, rt};                                     \
               _Pragma("unroll")                                         \
               for (int q = 0; q < 4; ++q) {                             \
                   vec2[2*q]   = __builtin_elementwise_fma(rt2, f32x2{EB[q].x, EB[q].y}, vec2[2*q]);   \
                   vec2[2*q+1] = __builtin_elementwise_fma(rt2, f32x2{EB[q].z, EB[q].w}, vec2[2*q+1]); \
               }                                                         \
               POUT = p; }
        for (int i = 0; i < CHUNK; i += 4) {
            float pv[4];
            P2STEP(C0, pv[0]);
            RELOAD(C0, kbase + i + 4);    // tail junk-safe (see pass 1 note)
            P2STEP(C1, pv[1]);
            RELOAD(C1, kbase + i + 5);
            P2STEP(C2, pv[2]);
            RELOAD(C2, kbase + i + 6);
            P2STEP(C3, pv[3]);
            RELOAD(C3, kbase + i + 7);
            // reduce pv[0..3] across 64 lanes (identical to r8):
            // array-halving butterfly (o=2,1) then o=4,8,16,32
            bool u2 = (lane & 2) != 0, u1 = (lane & 1) != 0;
            float t0 = (u2 ? pv[2] : pv[0]) + __shfl_xor(u2 ? pv[0] : pv[2], 2, 64);
            float t1 = (u2 ? pv[3] : pv[1]) + __shfl_xor(u2 ? pv[1] : pv[3], 2, 64);
            float v  = (u1 ? t1 : t0) + __shfl_xor(u1 ? t0 : t1, 1, 64);
            v += __shfl_xor(v, 4, 64);
            v += __shfl_xor(v, 8, 64);
            v += __shfl_xor(v, 16, 64);
            v += __shfl_xor(v, 32, 64);
            if (lane < 4) atomicAdd(&psum[kbase + i + lane], v);
        }
        #undef P2STEP
    }
    #undef RELOAD

    sst[w][lane] = St; sr[w][lane] = r;
    if (w >= 8) {
        #pragma unroll
        for (int q = 0; q < 8; ++q) {
            svec[w - 8][lane][2 * q]     = vec2[q].x;
            svec[w - 8][lane][2 * q + 1] = vec2[q].y;
        }
    }
    __syncthreads();
    if (w < 8) {
        #pragma unroll
        for (int q = 0; q < 8; ++q) {
            svec[w][lane][2 * q]     += vec2[q].x;
            svec[w][lane][2 * q + 1] += vec2[q].y;
        }
    }
    __syncthreads();

    // ---- epilogue (wave 0): combine + write outputs + sample-entropy
    if (w == 0) {
        float Stt = 0.f;
        #pragma unroll
        for (int j = 0; j < WAVES; ++j) Stt += sst[j][lane];
        float invSt = 1.0f / Stt;
        #pragma unroll
        for (int c = 0; c < ED; ++c) {
            float v = 0.f;
            #pragma unroll
            for (int j = 0; j < 8; ++j) v += svec[j][lane][c];
            out[OFF_SOFT + c * NPTS + n] = v * invSt;
        }
        out[OFF_IDX + n] = (float)AM;
        #pragma unroll
        for (int c = 0; c < ED; ++c)
            out[OFF_HARD + c * NPTS + n] = embN[AM * ED + c];
        // per-row sample term = ln(S1) - ln2 * Σ p·aK
        float rr = 0.f;
        #pragma unroll
        for (int j = 0; j < WAVES; ++j) rr += sr[j][lane];
        float row = logf(S1t) - LN2 * rr;
        #pragma unroll
        for (int off = 32; off > 0; off >>= 1) row += __shfl_xor(row, off, 64);
        if (lane == 0) atomicAdd(ssum, row);
    }
}

__global__ __launch_bounds__(256) void vq_finalize(const float* __restrict__ ws,
                                                   float* __restrict__ out) {
    __shared__ float red[4];
    float a = 0.f;
    for (int k = threadIdx.x; k < NE; k += 256) {
        float avg = ws[WS_PSUM + k] * (1.0f / 32768.0f);
        a += avg * logf(avg + 1e-6f);                 // = -avg_entropy contribution
    }
    #pragma unroll
    for (int off = 32; off > 0; off >>= 1) a += __shfl_xor(a, off, 64);
    if ((threadIdx.x & 63) == 0) red[threadIdx.x >> 6] = a;
    __syncthreads();
    if (threadIdx.x == 0) {
        float A = red[0] + red[1] + red[2] + red[3];  // A = -avg_entropy
        float sample = ws[WS_SSUM] * (1.0f / 32768.0f);
        out[OFF_LOSS] = 0.01f * (sample + A);         // ratio * (sample_ent - avg_ent)
    }
}

extern "C" void kernel_launch(void* const* d_in, const int* in_sizes, int n_in,
                              void* d_out, int out_size, void* d_ws, size_t ws_size,
                              hipStream_t stream) {
    const float* z   = (const float*)d_in[0];
    const float* emb = (const float*)d_in[1];
    float* out = (float*)d_out;
    float* ws  = (float*)d_ws;   // needs 34817 floats (~136 KB)

    vq_prep<<<(NE + 255) / 256, 256, 0, stream>>>(emb, ws);
    vq_main<<<NPTS / 64, WAVES * 64, 0, stream>>>(z, ws + WS_EMB, ws + WS_PSUM,
                                                  ws + WS_SSUM, out);
    vq_finalize<<<1, 256, 0, stream>>>(ws, out);
}

// Round 11
// 1074.278 us; speedup vs baseline: 1.4598x; 1.4598x over previous
//
#include <hip/hip_runtime.h>
#include <math.h>

typedef float f32x2 __attribute__((ext_vector_type(2)));

#define NPTS 32768          // b*h*w*d = 1*32*32*32
#define NE   2048
#define ED   16
#define WAVES 8
#define CHUNK (NE / WAVES)   // 256
#define HALFC (CHUNK / 2)    // 128

// exp2-domain temperature constants (exp(x*T) == exp2(x*T*log2e))
#define KT2 20.60992915555662f          // (1/0.07) * log2(e)
#define KE2 144.26950408889634f         // 100 * log2(e)
#define LN2 0.69314718055994531f

// output layout (floats, concatenated in return order)
#define OFF_SOFT 0
#define OFF_LOSS 524288
#define OFF_HARD 524289
#define OFF_IDX  1048577

// workspace layout (floats)
#define WS_EMB  0        // 2048*16 normalized embedding
#define WS_PSUM 32768    // 2048 column sums of ent-probs
#define WS_SSUM 34816    // 1 scalar

__device__ __forceinline__ float fexp2(float x) {
#if __has_builtin(__builtin_amdgcn_exp2f)
    return __builtin_amdgcn_exp2f(x);   // v_exp_f32
#else
    float r; asm("v_exp_f32 %0, %1" : "=v"(r) : "v"(x)); return r;
#endif
}

// dot over 16 channels with v_pk_fma_f32; accumulator partition identical to
// R8 (a.x=l0 a.y=l1 b.x=l2 b.y=l3, final (l0+l1)+(l2+l3))
// -> logits bit-identical vs R8's passing kernel (argmax unchanged).
__device__ __forceinline__ float dot16(const f32x2 zn2[8], const f32x2* __restrict__ e) {
    f32x2 a = zn2[0] * e[0];
    f32x2 b = zn2[1] * e[1];
    a = __builtin_elementwise_fma(zn2[2], e[2], a);
    b = __builtin_elementwise_fma(zn2[3], e[3], b);
    a = __builtin_elementwise_fma(zn2[4], e[4], a);
    b = __builtin_elementwise_fma(zn2[5], e[5], b);
    a = __builtin_elementwise_fma(zn2[6], e[6], a);
    b = __builtin_elementwise_fma(zn2[7], e[7], b);
    return (a.x + a.y) + (b.x + b.y);
}

__global__ __launch_bounds__(256) void vq_prep(const float* __restrict__ emb,
                                               float* __restrict__ ws) {
    int t = blockIdx.x * 256 + threadIdx.x;
    if (t < NE) {
        float v[ED]; float s = 0.f;
        #pragma unroll
        for (int c = 0; c < ED; ++c) { v[c] = emb[t * ED + c]; s += v[c] * v[c]; }
        float inv = 1.0f / fmaxf(sqrtf(s), 1e-12f);
        #pragma unroll
        for (int c = 0; c < ED; ++c) ws[WS_EMB + t * ED + c] = v[c] * inv;
        ws[WS_PSUM + t] = 0.f;
    }
    if (t == 0) ws[WS_SSUM] = 0.f;
}

__global__ __launch_bounds__(512, 6) void vq_main(const float* __restrict__ z,
                                                  const float* __restrict__ embN,
                                                  float* __restrict__ psum,
                                                  float* __restrict__ ssum,
                                                  float* __restrict__ out) {
    const int lane = threadIdx.x & 63;
    const int w    = threadIdx.x >> 6;   // divergent-typed: k addresses stay VMEM
    const int n    = blockIdx.x * 64 + lane;

    __shared__ float sm [WAVES][64];
    __shared__ float ss1[WAVES][64];
    __shared__ int   sam[WAVES][64];
    __shared__ float sst[WAVES][64];
    __shared__ float sr [WAVES][64];
    __shared__ float svec[WAVES / 2][64][ED + 1];   // +1 pad: conflict-free

    // ---- load z row (channel-strided) and l2-normalize (bit-identical to R8)
    float zn[ED]; float s = 0.f;
    #pragma unroll
    for (int c = 0; c < ED; ++c) { float v = z[c * NPTS + n]; zn[c] = v; s += v * v; }
    float rinv = 1.0f / fmaxf(sqrtf(s), 1e-12f);
    f32x2 zn2[8];
    #pragma unroll
    for (int q = 0; q < 8; ++q) zn2[q] = f32x2{zn[2 * q] * rinv, zn[2 * q + 1] * rinv};

    const int kbase = w * CHUNK;
    const f32x2* __restrict__ E = (const f32x2*)embN;   // 8 f32x2 per codeword

    // ---- pass 1: branchless online max/argmax/S1, two independent chains,
    //      VMEM broadcast loads (no readfirstlane -> no scalar-load path)
    float m0 = -2.f, m1 = -2.f, s10 = 0.f, s11 = 0.f;   // cosines in [-1,1]
    int am0 = kbase, am1 = kbase + HALFC;
    for (int i = 0; i < HALFC; ++i) {
        const f32x2* ea = E + (size_t)(kbase + i) * 8;
        const f32x2* eb = E + (size_t)(kbase + HALFC + i) * 8;
        float la = dot16(zn2, ea);
        float lb = dot16(zn2, eb);
        // chain 0: S1 = max? S1*e+1 : S1+e, with e = exp2(-|l-m|*K)
        float e0 = fexp2(-fabsf(la - m0) * KE2);
        bool  g0 = la > m0;
        am0 = g0 ? (kbase + i) : am0;
        m0  = fmaxf(m0, la);
        s10 = g0 ? fmaf(s10, e0, 1.0f) : (s10 + e0);
        // chain 1
        float e1 = fexp2(-fabsf(lb - m1) * KE2);
        bool  g1 = lb > m1;
        am1 = g1 ? (kbase + HALFC + i) : am1;
        m1  = fmaxf(m1, lb);
        s11 = g1 ? fmaf(s11, e1, 1.0f) : (s11 + e1);
    }
    {   // merge chains; chain0 owns lower k, so strict > keeps first max
        float em = fexp2(-fabsf(m1 - m0) * KE2);
        bool  g  = m1 > m0;
        sam[w][lane] = g ? am1 : am0;
        sm [w][lane] = fmaxf(m0, m1);
        ss1[w][lane] = g ? fmaf(s10, em, s11) : fmaf(s11, em, s10);
    }
    __syncthreads();

    // ---- flash-combine the 8 wave-chunks (every thread, own row)
    float M = sm[0][lane]; int AM = sam[0][lane];
    #pragma unroll
    for (int j = 1; j < WAVES; ++j) {
        float mj = sm[j][lane];
        if (mj > M) { M = mj; AM = sam[j][lane]; }    // ascending k: > keeps first
    }
    float S1t = 0.f;
    #pragma unroll
    for (int j = 0; j < WAVES; ++j)
        S1t += ss1[j][lane] * fexp2((sm[j][lane] - M) * KE2);
    float invS1 = 1.0f / S1t;

    // ---- pass 2: z_q_soft partials, tau-sum, entropy dot, avg_probs columns
    f32x2 vec2[8];
    #pragma unroll
    for (int q = 0; q < 8; ++q) vec2[q] = f32x2{0.f, 0.f};
    float St = 0.f, r = 0.f;
    for (int i = 0; i < CHUNK; i += 4) {
        float pv[4];
        #pragma unroll
        for (int j = 0; j < 4; ++j) {
            const f32x2* e = E + (size_t)(kbase + i + j) * 8;
            float l  = dot16(zn2, e);
            float aa = l - M;                         // <= 0 (same dot order as pass 1)
            float aK = aa * KE2;
            float rt = fexp2(aa * KT2);               // tau weight (unnormalized)
            St += rt;
            float p  = fexp2(aK) * invS1;             // normalized ent prob
            r = fmaf(p, aK, r);                       // Σ p·a·100·log2e
            f32x2 rt2 = {rt, rt};
            #pragma unroll
            for (int q = 0; q < 8; ++q)
                vec2[q] = __builtin_elementwise_fma(rt2, e[q], vec2[q]);
            pv[j] = p;
        }
        // reduce pv[0..3] across 64 lanes: array-halving butterfly (o=2,1),
        // then single-value butterfly (o=4,8,16,32). lane l ends with k-offset l&3.
        bool u2 = (lane & 2) != 0, u1 = (lane & 1) != 0;
        float t0 = (u2 ? pv[2] : pv[0]) + __shfl_xor(u2 ? pv[0] : pv[2], 2, 64);
        float t1 = (u2 ? pv[3] : pv[1]) + __shfl_xor(u2 ? pv[1] : pv[3], 2, 64);
        float v  = (u1 ? t1 : t0) + __shfl_xor(u1 ? t0 : t1, 1, 64);
        v += __shfl_xor(v, 4, 64);
        v += __shfl_xor(v, 8, 64);
        v += __shfl_xor(v, 16, 64);
        v += __shfl_xor(v, 32, 64);
        if (lane < 4) atomicAdd(&psum[kbase + i + lane], v);
    }

    sst[w][lane] = St; sr[w][lane] = r;
    // ---- svec fold: svec[j] = vec(j) + vec(j+4)
    if (w >= 4) {
        #pragma unroll
        for (int q = 0; q < 8; ++q) {
            svec[w - 4][lane][2 * q]     = vec2[q].x;
            svec[w - 4][lane][2 * q + 1] = vec2[q].y;
        }
    }
    __syncthreads();
    if (w < 4) {
        #pragma unroll
        for (int q = 0; q < 8; ++q) {
            svec[w][lane][2 * q]     += vec2[q].x;
            svec[w][lane][2 * q + 1] += vec2[q].y;
        }
    }
    __syncthreads();

    // ---- epilogue (wave 0): combine + write outputs + sample-entropy
    if (w == 0) {
        float Stt = 0.f;
        #pragma unroll
        for (int j = 0; j < WAVES; ++j) Stt += sst[j][lane];
        float invSt = 1.0f / Stt;
        #pragma unroll
        for (int c = 0; c < ED; ++c) {
            float v = svec[0][lane][c] + svec[1][lane][c]
                    + svec[2][lane][c] + svec[3][lane][c];
            out[OFF_SOFT + c * NPTS + n] = v * invSt;
        }
        out[OFF_IDX + n] = (float)AM;
        #pragma unroll
        for (int c = 0; c < ED; ++c)
            out[OFF_HARD + c * NPTS + n] = embN[AM * ED + c];
        // per-row sample term = ln(S1) - ln2 * Σ p·aK
        float rr = 0.f;
        #pragma unroll
        for (int j = 0; j < WAVES; ++j) rr += sr[j][lane];
        float row = logf(S1t) - LN2 * rr;
        #pragma unroll
        for (int off = 32; off > 0; off >>= 1) row += __shfl_xor(row, off, 64);
        if (lane == 0) atomicAdd(ssum, row);
    }
}

__global__ __launch_bounds__(256) void vq_finalize(const float* __restrict__ ws,
                                                   float* __restrict__ out) {
    __shared__ float red[4];
    float a = 0.f;
    for (int k = threadIdx.x; k < NE; k += 256) {
        float avg = ws[WS_PSUM + k] * (1.0f / 32768.0f);
        a += avg * logf(avg + 1e-6f);                 // = -avg_entropy contribution
    }
    #pragma unroll
    for (int off = 32; off > 0; off >>= 1) a += __shfl_xor(a, off, 64);
    if ((threadIdx.x & 63) == 0) red[threadIdx.x >> 6] = a;
    __syncthreads();
    if (threadIdx.x == 0) {
        float A = red[0] + red[1] + red[2] + red[3];  // A = -avg_entropy
        float sample = ws[WS_SSUM] * (1.0f / 32768.0f);
        out[OFF_LOSS] = 0.01f * (sample + A);         // ratio * (sample_ent - avg_ent)
    }
}

extern "C" void kernel_launch(void* const* d_in, const int* in_sizes, int n_in,
                              void* d_out, int out_size, void* d_ws, size_t ws_size,
                              hipStream_t stream) {
    const float* z   = (const float*)d_in[0];
    const float* emb = (const float*)d_in[1];
    float* out = (float*)d_out;
    float* ws  = (float*)d_ws;   // needs 34817 floats (~136 KB)

    vq_prep<<<(NE + 255) / 256, 256, 0, stream>>>(emb, ws);
    vq_main<<<NPTS / 64, WAVES * 64, 0, stream>>>(z, ws + WS_EMB, ws + WS_PSUM,
                                                  ws + WS_SSUM, out);
    vq_finalize<<<1, 256, 0, stream>>>(ws, out);
}

// Round 12
// 178.006 us; speedup vs baseline: 8.8099x; 6.0351x over previous
//
#include <hip/hip_runtime.h>
#include <math.h>

typedef float f32x2 __attribute__((ext_vector_type(2)));

#define NPTS 32768          // b*h*w*d = 1*32*32*32
#define NE   2048
#define ED   16
#define WAVES 16
#define CHUNK (NE / WAVES)   // 128
#define HALFC (CHUNK / 2)    // 64

// exp2-domain temperature constants (exp(x*T) == exp2(x*T*log2e))
#define KT2 20.60992915555662f          // (1/0.07) * log2(e)
#define KE2 144.26950408889634f         // 100 * log2(e)
#define LN2 0.69314718055994531f

// output layout (floats, concatenated in return order)
#define OFF_SOFT 0
#define OFF_LOSS 524288
#define OFF_HARD 524289
#define OFF_IDX  1048577

// workspace layout (floats)
#define WS_EMB  0        // 2048*16 normalized embedding
#define WS_PSUM 32768    // 2048 column sums of ent-probs
#define WS_SSUM 34816    // 1 scalar

__device__ __forceinline__ float fexp2(float x) {
#if __has_builtin(__builtin_amdgcn_exp2f)
    return __builtin_amdgcn_exp2f(x);   // v_exp_f32
#else
    float r; asm("v_exp_f32 %0, %1" : "=v"(r) : "v"(x)); return r;
#endif
}

// DPP cross-lane move (VALU pipe, no DS op / no lgkmcnt):
// 0xB1 = quad_perm[1,0,3,2] (xor-1), 0x4E = quad_perm[2,3,0,1] (xor-2),
// 0x128 = row_ror:8 (== xor-8 within each 16-lane row).
// All lanes active at every call site -> bound_ctrl/old irrelevant.
template <int CTRL>
__device__ __forceinline__ float dppmov(float x) {
    int yi = __builtin_amdgcn_update_dpp(0, __builtin_bit_cast(int, x),
                                         CTRL, 0xF, 0xF, true);
    return __builtin_bit_cast(float, yi);
}

// dot over 16 channels with v_pk_fma_f32; accumulator partition identical to
// the scalar l0..l3 version (a.x=l0 a.y=l1 b.x=l2 b.y=l3, final (l0+l1)+(l2+l3))
// -> bit-identical logits vs the round-8 passing kernel (argmax unchanged).
__device__ __forceinline__ float dot16(const f32x2 zn2[8], const f32x2* __restrict__ e) {
    f32x2 a = zn2[0] * e[0];
    f32x2 b = zn2[1] * e[1];
    a = __builtin_elementwise_fma(zn2[2], e[2], a);
    b = __builtin_elementwise_fma(zn2[3], e[3], b);
    a = __builtin_elementwise_fma(zn2[4], e[4], a);
    b = __builtin_elementwise_fma(zn2[5], e[5], b);
    a = __builtin_elementwise_fma(zn2[6], e[6], a);
    b = __builtin_elementwise_fma(zn2[7], e[7], b);
    return (a.x + a.y) + (b.x + b.y);
}

__global__ __launch_bounds__(256) void vq_prep(const float* __restrict__ emb,
                                               float* __restrict__ ws) {
    int t = blockIdx.x * 256 + threadIdx.x;
    if (t < NE) {
        float v[ED]; float s = 0.f;
        #pragma unroll
        for (int c = 0; c < ED; ++c) { v[c] = emb[t * ED + c]; s += v[c] * v[c]; }
        float inv = 1.0f / fmaxf(sqrtf(s), 1e-12f);
        #pragma unroll
        for (int c = 0; c < ED; ++c) ws[WS_EMB + t * ED + c] = v[c] * inv;
        ws[WS_PSUM + t] = 0.f;
    }
    if (t == 0) ws[WS_SSUM] = 0.f;
}

__global__ __launch_bounds__(1024, 6) void vq_main(const float* __restrict__ z,
                                                   const float* __restrict__ embN,
                                                   float* __restrict__ psum,
                                                   float* __restrict__ ssum,
                                                   float* __restrict__ out) {
    const int lane = threadIdx.x & 63;
    const int w    = threadIdx.x >> 6;
    const int n    = blockIdx.x * 64 + lane;

    __shared__ float sm [WAVES][64];
    __shared__ float ss1[WAVES][64];
    __shared__ int   sam[WAVES][64];
    __shared__ float sst[WAVES][64];
    __shared__ float sr [WAVES][64];
    __shared__ float svec[WAVES / 2][64][ED + 1];   // +1 pad: conflict-free

    // ---- load z row (channel-strided) and l2-normalize (bit-identical to r8)
    float zn[ED]; float s = 0.f;
    #pragma unroll
    for (int c = 0; c < ED; ++c) { float v = z[c * NPTS + n]; zn[c] = v; s += v * v; }
    float rinv = 1.0f / fmaxf(sqrtf(s), 1e-12f);
    f32x2 zn2[8];
    #pragma unroll
    for (int q = 0; q < 8; ++q) zn2[q] = f32x2{zn[2 * q] * rinv, zn[2 * q + 1] * rinv};

    const int kbase = w * CHUNK;
    const f32x2* __restrict__ E = (const f32x2*)embN;   // 8 f32x2 per codeword

    // ---- pass 1: branchless online max/argmax/S1, two independent chains,
    //      wave-uniform s_load broadcast via readfirstlane (proven fetch path)
    float m0 = -2.f, m1 = -2.f, s10 = 0.f, s11 = 0.f;   // cosines in [-1,1]
    int am0 = kbase, am1 = kbase + HALFC;
    for (int i = 0; i < HALFC; ++i) {
        int ka = __builtin_amdgcn_readfirstlane(kbase + i);
        int kb = __builtin_amdgcn_readfirstlane(kbase + HALFC + i);
        float la = dot16(zn2, E + (size_t)ka * 8);
        float lb = dot16(zn2, E + (size_t)kb * 8);
        // chain 0: S1 = max? S1*e+1 : S1+e, with e = exp2(-|l-m|*K)
        float e0 = fexp2(-fabsf(la - m0) * KE2);
        bool  g0 = la > m0;
        am0 = g0 ? (kbase + i) : am0;
        m0  = fmaxf(m0, la);
        s10 = g0 ? fmaf(s10, e0, 1.0f) : (s10 + e0);
        // chain 1
        float e1 = fexp2(-fabsf(lb - m1) * KE2);
        bool  g1 = lb > m1;
        am1 = g1 ? (kbase + HALFC + i) : am1;
        m1  = fmaxf(m1, lb);
        s11 = g1 ? fmaf(s11, e1, 1.0f) : (s11 + e1);
    }
    {   // merge chains; chain0 owns lower k, so strict > keeps first max
        float em = fexp2(-fabsf(m1 - m0) * KE2);
        bool  g  = m1 > m0;
        sam[w][lane] = g ? am1 : am0;
        sm [w][lane] = fmaxf(m0, m1);
        ss1[w][lane] = g ? fmaf(s10, em, s11) : fmaf(s11, em, s10);
    }
    __syncthreads();

    // ---- flash-combine the 16 wave-chunks (every thread, own row)
    float M = sm[0][lane]; int AM = sam[0][lane];
    #pragma unroll
    for (int j = 1; j < WAVES; ++j) {
        float mj = sm[j][lane];
        if (mj > M) { M = mj; AM = sam[j][lane]; }    // ascending k: > keeps first
    }
    float S1t = 0.f;
    #pragma unroll
    for (int j = 0; j < WAVES; ++j)
        S1t += ss1[j][lane] * fexp2((sm[j][lane] - M) * KE2);
    float invS1 = 1.0f / S1t;

    // ---- pass 2: z_q_soft partials, tau-sum, entropy dot, avg_probs columns.
    //      Batch-8 reduction: xor-4 shfl, xor-2/1 DPP, xor-8 DPP, xor-16/32 shfl
    //      -> 6 DS ops per 8 k (was 14), fewer lgkmcnt drains of the s_load queue.
    f32x2 vec2[8];
    #pragma unroll
    for (int q = 0; q < 8; ++q) vec2[q] = f32x2{0.f, 0.f};
    float St = 0.f, r = 0.f;
    for (int i = 0; i < CHUNK; i += 8) {
        float pv[8];
        #pragma unroll
        for (int j = 0; j < 8; ++j) {
            int ku = __builtin_amdgcn_readfirstlane(kbase + i + j);
            const f32x2* e = E + (size_t)ku * 8;
            float l  = dot16(zn2, e);
            float aa = l - M;                         // <= 0 (same dot order as pass 1)
            float aK = aa * KE2;
            float rt = fexp2(aa * KT2);               // tau weight (unnormalized)
            St += rt;
            float p  = fexp2(aK) * invS1;             // normalized ent prob
            r = fmaf(p, aK, r);                       // Σ p·a·100·log2e
            f32x2 rt2 = {rt, rt};
            #pragma unroll
            for (int q = 0; q < 8; ++q)
                vec2[q] = __builtin_elementwise_fma(rt2, e[q], vec2[q]);
            pv[j] = p;
        }
        // halving butterfly across 64 rows; lane l ends with slot (l&7), all
        // lanes hold the 64-row total for their slot.
        bool u4 = (lane & 4) != 0, u2 = (lane & 2) != 0, u1 = (lane & 1) != 0;
        float t0 = (u4 ? pv[4] : pv[0]) + __shfl_xor(u4 ? pv[0] : pv[4], 4, 64);
        float t1 = (u4 ? pv[5] : pv[1]) + __shfl_xor(u4 ? pv[1] : pv[5], 4, 64);
        float t2 = (u4 ? pv[6] : pv[2]) + __shfl_xor(u4 ? pv[2] : pv[6], 4, 64);
        float t3 = (u4 ? pv[7] : pv[3]) + __shfl_xor(u4 ? pv[3] : pv[7], 4, 64);
        float s0 = (u2 ? t2 : t0) + dppmov<0x4E>(u2 ? t0 : t2);   // xor-2 (DPP)
        float s1 = (u2 ? t3 : t1) + dppmov<0x4E>(u2 ? t1 : t3);
        float v  = (u1 ? s1 : s0) + dppmov<0xB1>(u1 ? s0 : s1);   // xor-1 (DPP)
        v += dppmov<0x128>(v);                                    // xor-8 (DPP)
        v += __shfl_xor(v, 16, 64);
        v += __shfl_xor(v, 32, 64);
        if (lane < 8) atomicAdd(&psum[kbase + i + lane], v);
    }

    sst[w][lane] = St; sr[w][lane] = r;
    if (w >= 8) {
        #pragma unroll
        for (int q = 0; q < 8; ++q) {
            svec[w - 8][lane][2 * q]     = vec2[q].x;
            svec[w - 8][lane][2 * q + 1] = vec2[q].y;
        }
    }
    __syncthreads();
    if (w < 8) {
        #pragma unroll
        for (int q = 0; q < 8; ++q) {
            svec[w][lane][2 * q]     += vec2[q].x;
            svec[w][lane][2 * q + 1] += vec2[q].y;
        }
    }
    __syncthreads();

    // ---- epilogue (wave 0): combine + write outputs + sample-entropy
    if (w == 0) {
        float Stt = 0.f;
        #pragma unroll
        for (int j = 0; j < WAVES; ++j) Stt += sst[j][lane];
        float invSt = 1.0f / Stt;
        #pragma unroll
        for (int c = 0; c < ED; ++c) {
            float v = 0.f;
            #pragma unroll
            for (int j = 0; j < 8; ++j) v += svec[j][lane][c];
            out[OFF_SOFT + c * NPTS + n] = v * invSt;
        }
        out[OFF_IDX + n] = (float)AM;
        #pragma unroll
        for (int c = 0; c < ED; ++c)
            out[OFF_HARD + c * NPTS + n] = embN[AM * ED + c];
        // per-row sample term = ln(S1) - ln2 * Σ p·aK
        float rr = 0.f;
        #pragma unroll
        for (int j = 0; j < WAVES; ++j) rr += sr[j][lane];
        float row = logf(S1t) - LN2 * rr;
        #pragma unroll
        for (int off = 32; off > 0; off >>= 1) row += __shfl_xor(row, off, 64);
        if (lane == 0) atomicAdd(ssum, row);
    }
}

__global__ __launch_bounds__(256) void vq_finalize(const float* __restrict__ ws,
                                                   float* __restrict__ out) {
    __shared__ float red[4];
    float a = 0.f;
    for (int k = threadIdx.x; k < NE; k += 256) {
        float avg = ws[WS_PSUM + k] * (1.0f / 32768.0f);
        a += avg * logf(avg + 1e-6f);                 // = -avg_entropy contribution
    }
    #pragma unroll
    for (int off = 32; off > 0; off >>= 1) a += __shfl_xor(a, off, 64);
    if ((threadIdx.x & 63) == 0) red[threadIdx.x >> 6] = a;
    __syncthreads();
    if (threadIdx.x == 0) {
        float A = red[0] + red[1] + red[2] + red[3];  // A = -avg_entropy
        float sample = ws[WS_SSUM] * (1.0f / 32768.0f);
        out[OFF_LOSS] = 0.01f * (sample + A);         // ratio * (sample_ent - avg_ent)
    }
}

extern "C" void kernel_launch(void* const* d_in, const int* in_sizes, int n_in,
                              void* d_out, int out_size, void* d_ws, size_t ws_size,
                              hipStream_t stream) {
    const float* z   = (const float*)d_in[0];
    const float* emb = (const float*)d_in[1];
    float* out = (float*)d_out;
    float* ws  = (float*)d_ws;   // needs 34817 floats (~136 KB)

    vq_prep<<<(NE + 255) / 256, 256, 0, stream>>>(emb, ws);
    vq_main<<<NPTS / 64, WAVES * 64, 0, stream>>>(z, ws + WS_EMB, ws + WS_PSUM,
                                                  ws + WS_SSUM, out);
    vq_finalize<<<1, 256, 0, stream>>>(ws, out);
}